// Round 9
// baseline (288.000 us; speedup 1.0000x reference)
//
#include <hip/hip_runtime.h>
#include <stdint.h>

// Problem constants (fixed by reference)
#define NN 100000      // nodes
#define NE 1600000     // edges
#define K_DIM 128      // IN_DIM == HID_DIM

// Coarse binning for CSR build
#define BSH 7                                   // 128 nodes per bucket
#define NBKT ((NN + (1 << BSH) - 1) >> BSH)     // 782 buckets
#define EPT 32                                  // edges per thread, pass 1
#define BIN_CHUNK (256 * EPT)                   // 8192 edges per block
#define CAP 4096                                // staging/ssrc stride per bucket (exp 2046, sigma 45)

typedef unsigned int uint32;
typedef unsigned short ushort16;
typedef __attribute__((ext_vector_type(8))) short bf16x8;
typedef __attribute__((ext_vector_type(4))) float f32x4;

__device__ __forceinline__ ushort16 f2bf(float f) {
    uint32 u = __float_as_uint(f);
    u += 0x7fffu + ((u >> 16) & 1u);   // round-to-nearest-even
    return (ushort16)(u >> 16);
}
__device__ __forceinline__ float bf_lo(uint32 u) { return __uint_as_float(u << 16); }
__device__ __forceinline__ float bf_hi(uint32 u) { return __uint_as_float(u & 0xffff0000u); }

// Accumulate 8 bf16 (packed in uint4) into acc[0..7]
__device__ __forceinline__ void acc8(float* acc, uint4 v) {
    acc[0] += bf_lo(v.x); acc[1] += bf_hi(v.x);
    acc[2] += bf_lo(v.y); acc[3] += bf_hi(v.y);
    acc[4] += bf_lo(v.z); acc[5] += bf_hi(v.z);
    acc[6] += bf_lo(v.w); acc[7] += bf_hi(v.w);
}

// Load an 8-bf16 MFMA fragment from LDS as 2x ds_read_b64 (8B-aligned, LDA=132)
__device__ __forceinline__ bf16x8 ld_frag8(const ushort16* p) {
    uint2 lo = *(const uint2*)p;
    uint2 hi = *(const uint2*)(p + 4);
    union { uint32 u[4]; bf16x8 v; } x;
    x.u[0] = lo.x; x.u[1] = lo.y; x.u[2] = hi.x; x.u[3] = hi.y;
    return x.v;
}

// ---------------------------------------------------------------------------
// CSR build: pass1 fixed-stride bucket scatter -> csr_build (count + local
// scan + fine scatter + pad fill, all per-bucket). No global random atomics,
// no global scan.
// ---------------------------------------------------------------------------

// Pass 1: bin (src,dst) pairs into fixed-stride coarse buckets (write-combining).
__global__ __launch_bounds__(256) void bin_pass1_kernel(
        const int* __restrict__ ei, int* __restrict__ gcursor,
        uint2* __restrict__ staging) {
    __shared__ int hist[NBKT];
    __shared__ int base[NBKT];
    int tid = threadIdx.x;
    int e0 = blockIdx.x * BIN_CHUNK;

    for (int i = tid; i < NBKT; i += 256) hist[i] = 0;
    __syncthreads();

    #pragma unroll
    for (int k = 0; k < EPT; k++) {
        int e = e0 + k * 256 + tid;
        if (e < NE) {
            int d = ei[NE + e];
            atomicAdd(&hist[d >> BSH], 1);
        }
    }
    __syncthreads();

    for (int i = tid; i < NBKT; i += 256) {
        int c = hist[i];
        base[i] = c ? atomicAdd(&gcursor[i], c) : 0;
        hist[i] = 0;
    }
    __syncthreads();

    #pragma unroll
    for (int k = 0; k < EPT; k++) {
        int e = e0 + k * 256 + tid;
        if (e < NE) {
            int s = ei[e];
            int d = ei[NE + e];
            int b = d >> BSH;
            int off = atomicAdd(&hist[b], 1);
            staging[(size_t)b * CAP + base[b] + off] = make_uint2((uint32)s, (uint32)d);
        }
    }
}

// One block per bucket: LDS degree count -> dis + local exclusive scan of
// padded degrees -> row_start/row_end (bucket-local, base b*CAP) -> fine
// scatter into ssrc -> pad fill with dummy NN (zero row).
__global__ __launch_bounds__(256) void csr_build_kernel(
        const uint2* __restrict__ staging, const int* __restrict__ gcursor,
        float* __restrict__ dis, int* __restrict__ row_start, int* __restrict__ row_end,
        int* __restrict__ ssrc) {
    __shared__ int cnt[1 << BSH];
    __shared__ int sb[1 << BSH];
    __shared__ int cur[1 << BSH];
    __shared__ int pend[1 << BSH];
    int b = blockIdx.x;
    int node0 = b << BSH;
    int tid = threadIdx.x;
    int n_edges = gcursor[b];

    if (tid < (1 << BSH)) cnt[tid] = 0;
    __syncthreads();

    for (int i = tid; i < n_edges; i += 256) {
        uint2 p = staging[(size_t)b * CAP + i];
        atomicAdd(&cnt[p.y & ((1 << BSH) - 1)], 1);
    }
    __syncthreads();

    int p = 0;
    if (tid < (1 << BSH)) {
        int node = node0 + tid;
        p = (node < NN) ? ((cnt[tid] + 7) & ~7) : 0;
        sb[tid] = p;
    }
    __syncthreads();
    #pragma unroll
    for (int off = 1; off < (1 << BSH); off <<= 1) {
        int t = (tid >= off && tid < (1 << BSH)) ? sb[tid - off] : 0;
        __syncthreads();
        if (tid < (1 << BSH)) sb[tid] += t;
        __syncthreads();
    }
    if (tid < (1 << BSH)) {
        int rs = b * CAP + sb[tid] - p;     // exclusive, bucket-local
        cur[tid] = rs;
        pend[tid] = rs + p;
        int node = node0 + tid;
        if (node < NN) {
            row_start[node] = rs;
            row_end[node] = rs + p;
            int c = cnt[tid];
            dis[node] = (c > 0) ? rsqrtf((float)c) : 0.0f;
        }
    }
    __syncthreads();

    for (int i = tid; i < n_edges; i += 256) {
        uint2 pr = staging[(size_t)b * CAP + i];
        int off = atomicAdd(&cur[pr.y & ((1 << BSH) - 1)], 1);
        ssrc[off] = (int)pr.x;
    }
    __syncthreads();

    if (tid < (1 << BSH)) {
        int node = node0 + tid;
        if (node < NN) {
            for (int q = cur[tid]; q < pend[tid]; q++) ssrc[q] = NN;   // dummy -> zero row
        }
    }
}

// ---------------------------------------------------------------------------
// MFMA bf16 GEMM: out[M,N] = bf16( (A[M,128] @ W[128,N]) * dis[row] )
// BM=64, full K=128 resident in LDS, one barrier per block.
// ---------------------------------------------------------------------------
template <int N, bool ABF16>
__global__ __launch_bounds__(256) void gemm_mfma_kernel(
        const void* __restrict__ Ap, const float* __restrict__ W,
        const float* __restrict__ dis, ushort16* __restrict__ out, int M) {
    constexpr int BM = 64, K = K_DIM;
    constexpr int LDA = 132;
    constexpr int NT = N / 16;
    constexpr int NLOG = (N == 128) ? 7 : 6;

    __shared__ ushort16 As[BM * LDA];
    __shared__ ushort16 Bt[N * LDA];

    int tid = threadIdx.x;
    int row0 = blockIdx.x * BM;

    if constexpr (!ABF16) {
        const float* A = (const float*)Ap;
        #pragma unroll
        for (int c = 0; c < 8; c++) {
            int idx = c * 1024 + tid * 4;
            int r = idx >> 7, col = idx & 127;
            int ra = row0 + r;
            float4 v = (ra < M) ? *(const float4*)&A[(size_t)ra * K + col]
                                : make_float4(0.f, 0.f, 0.f, 0.f);
            ushort4 bq;
            bq.x = f2bf(v.x); bq.y = f2bf(v.y); bq.z = f2bf(v.z); bq.w = f2bf(v.w);
            *(ushort4*)&As[r * LDA + col] = bq;
        }
    } else {
        const ushort16* A = (const ushort16*)Ap;
        #pragma unroll
        for (int c = 0; c < 4; c++) {
            int idx = c * 2048 + tid * 8;
            int r = idx >> 7, col = idx & 127;
            int ra = row0 + r;
            uint4 v = make_uint4(0u, 0u, 0u, 0u);
            if (ra < M) v = *(const uint4*)&A[(size_t)ra * K + col];
            *(uint2*)&As[r * LDA + col]     = make_uint2(v.x, v.y);
            *(uint2*)&As[r * LDA + col + 4] = make_uint2(v.z, v.w);
        }
    }
    {
        #pragma unroll
        for (int c = 0; c < (K * N) / 1024; c++) {
            int idx = c * 1024 + tid * 4;
            int k = idx >> NLOG, n = idx & (N - 1);
            float4 v = *(const float4*)&W[idx];
            Bt[(n + 0) * LDA + k] = f2bf(v.x);
            Bt[(n + 1) * LDA + k] = f2bf(v.y);
            Bt[(n + 2) * LDA + k] = f2bf(v.z);
            Bt[(n + 3) * LDA + k] = f2bf(v.w);
        }
    }
    __syncthreads();

    int lane = tid & 63;
    int wv = tid >> 6;
    int m0 = wv * 16;
    int ml = lane & 15;
    int quad = lane >> 4;

    f32x4 acc[NT];
    #pragma unroll
    for (int i = 0; i < NT; i++) acc[i] = (f32x4){0.f, 0.f, 0.f, 0.f};

    #pragma unroll
    for (int ks = 0; ks < 4; ks++) {
        int kof = ks * 32 + quad * 8;
        bf16x8 a = ld_frag8(&As[(m0 + ml) * LDA + kof]);
        #pragma unroll
        for (int nt = 0; nt < NT; nt++) {
            bf16x8 bb = ld_frag8(&Bt[(nt * 16 + ml) * LDA + kof]);
            acc[nt] = __builtin_amdgcn_mfma_f32_16x16x32_bf16(a, bb, acc[nt], 0, 0, 0);
        }
    }

    #pragma unroll
    for (int r = 0; r < 4; r++) {
        int row = row0 + m0 + quad * 4 + r;
        if (row < M) {
            float s = dis[row];
            #pragma unroll
            for (int nt = 0; nt < NT; nt++)
                out[(size_t)row * N + nt * 16 + ml] = f2bf(acc[nt][r] * s);
        }
    }
}

// ---------------------------------------------------------------------------
// Aggregation layer 1: F=128 bf16 rows (256B). One wave per node.
// 16 lanes/row x 16B loads; 4 edge-groups/wave -> one load instruction
// gathers 4 rows (1KB). Padded CSR: batches of 8, no tail.
// out bf16 with ReLU.
// ---------------------------------------------------------------------------
__global__ __launch_bounds__(256) void agg128_kernel(
        const ushort16* __restrict__ g, const int* __restrict__ row_start,
        const int* __restrict__ row_end, const int* __restrict__ ssrc,
        const float* __restrict__ dis, const float* __restrict__ bias,
        ushort16* __restrict__ out) {
    int wave = (blockIdx.x * 256 + threadIdx.x) >> 6;
    int lane = threadIdx.x & 63;
    if (wave >= NN) return;

    int f = lane & 15;        // feature slice: 8 bf16 at col f*8
    int gq = lane >> 4;       // edge group 0..3

    int beg = row_start[wave];
    int end = row_end[wave];
    float sc = dis[wave];

    float acc[8] = {};
    for (int e = beg; e < end; e += 8) {
        int idx = ssrc[e + (lane & 7)];
        #pragma unroll
        for (int j = 0; j < 2; j++) {
            int s = __shfl(idx, gq * 2 + j);
            uint4 v = *(const uint4*)&g[(size_t)s * 128 + f * 8];
            acc8(acc, v);
        }
    }
    #pragma unroll
    for (int i = 0; i < 8; i++) {
        acc[i] += __shfl_xor(acc[i], 16);
        acc[i] += __shfl_xor(acc[i], 32);
    }
    if (gq == 0) {
        float4 b0 = *(const float4*)&bias[f * 8];
        float4 b1 = *(const float4*)&bias[f * 8 + 4];
        float o0 = fmaxf(sc * acc[0] + b0.x, 0.f);
        float o1 = fmaxf(sc * acc[1] + b0.y, 0.f);
        float o2 = fmaxf(sc * acc[2] + b0.z, 0.f);
        float o3 = fmaxf(sc * acc[3] + b0.w, 0.f);
        float o4 = fmaxf(sc * acc[4] + b1.x, 0.f);
        float o5 = fmaxf(sc * acc[5] + b1.y, 0.f);
        float o6 = fmaxf(sc * acc[6] + b1.z, 0.f);
        float o7 = fmaxf(sc * acc[7] + b1.w, 0.f);
        uint4 pk;
        pk.x = ((uint32)f2bf(o1) << 16) | (uint32)f2bf(o0);
        pk.y = ((uint32)f2bf(o3) << 16) | (uint32)f2bf(o2);
        pk.z = ((uint32)f2bf(o5) << 16) | (uint32)f2bf(o4);
        pk.w = ((uint32)f2bf(o7) << 16) | (uint32)f2bf(o6);
        *(uint4*)&out[(size_t)wave * 128 + f * 8] = pk;
    }
}

// ---------------------------------------------------------------------------
// Aggregation layer 2: F=64 bf16 rows (128B). One wave per node.
// 8 lanes/row x 16B loads; 8 edge-groups/wave -> one load instruction
// gathers 8 rows (1KB). f32 output (no activation).
// ---------------------------------------------------------------------------
__global__ __launch_bounds__(256) void agg64_kernel(
        const ushort16* __restrict__ g, const int* __restrict__ row_start,
        const int* __restrict__ row_end, const int* __restrict__ ssrc,
        const float* __restrict__ dis, const float* __restrict__ bias,
        float* __restrict__ out) {
    int wave = (blockIdx.x * 256 + threadIdx.x) >> 6;
    int lane = threadIdx.x & 63;
    if (wave >= NN) return;

    int f = lane & 7;         // feature slice: 8 bf16 at col f*8
    int gq = lane >> 3;       // edge group 0..7

    int beg = row_start[wave];
    int end = row_end[wave];
    float sc = dis[wave];

    float acc[8] = {};
    for (int e = beg; e < end; e += 8) {
        int idx = ssrc[e + (lane & 7)];
        int s = __shfl(idx, gq);
        uint4 v = *(const uint4*)&g[(size_t)s * 64 + f * 8];
        acc8(acc, v);
    }
    #pragma unroll
    for (int i = 0; i < 8; i++) {
        acc[i] += __shfl_xor(acc[i], 8);
        acc[i] += __shfl_xor(acc[i], 16);
        acc[i] += __shfl_xor(acc[i], 32);
    }
    if (gq == 0) {
        float4 b0 = *(const float4*)&bias[f * 8];
        float4 b1 = *(const float4*)&bias[f * 8 + 4];
        float4 o0, o1;
        o0.x = sc * acc[0] + b0.x; o0.y = sc * acc[1] + b0.y;
        o0.z = sc * acc[2] + b0.z; o0.w = sc * acc[3] + b0.w;
        o1.x = sc * acc[4] + b1.x; o1.y = sc * acc[5] + b1.y;
        o1.z = sc * acc[6] + b1.z; o1.w = sc * acc[7] + b1.w;
        *(float4*)&out[(size_t)wave * 64 + f * 8] = o0;
        *(float4*)&out[(size_t)wave * 64 + f * 8 + 4] = o1;
    }
}

// ---------------------------------------------------------------------------
// Launch
// ---------------------------------------------------------------------------
extern "C" void kernel_launch(void* const* d_in, const int* in_sizes, int n_in,
                              void* d_out, int out_size, void* d_ws, size_t ws_size,
                              hipStream_t stream) {
    const float* x  = (const float*)d_in[0];
    const int*   ei = (const int*)d_in[1];
    const float* W1 = (const float*)d_in[2];
    const float* b1 = (const float*)d_in[3];
    const float* W2 = (const float*)d_in[4];
    const float* b2 = (const float*)d_in[5];
    float* out = (float*)d_out;

    char* ws = (char*)d_ws;
    size_t off = 0;
    auto alloc = [&](size_t bytes) {
        void* p = ws + off;
        off = (off + bytes + 255) & ~(size_t)255;
        return p;
    };

    float*    dis        = (float*)alloc(NN * 4);
    int*      row_start  = (int*)alloc(NN * 4);
    int*      row_end    = (int*)alloc(NN * 4);
    int*      gcursor    = (int*)alloc(NBKT * 4);
    int*      ssrc       = (int*)alloc((size_t)NBKT * CAP * 4);       // 12.8 MB
    ushort16* g1         = (ushort16*)alloc((size_t)(NN + 1) * 128 * 2);  // +zero row
    // staging (25.62 MB) and h (25.6 MB) share one region: staging is dead
    // after csr_build (before gemm128), h written first by agg128.
    char*     big        = (char*)alloc((size_t)NBKT * CAP * 8);
    uint2*    staging    = (uint2*)big;
    ushort16* h          = (ushort16*)big;
    ushort16* g2         = g1;               // alias: g1 dead after agg1

    hipMemsetAsync(gcursor, 0, NBKT * 4, stream);
    hipMemsetAsync((char*)g1 + (size_t)NN * 256, 0, 256, stream);   // g1 zero row

    bin_pass1_kernel<<<(NE + BIN_CHUNK - 1) / BIN_CHUNK, 256, 0, stream>>>(ei, gcursor, staging);
    csr_build_kernel<<<NBKT, 256, 0, stream>>>(staging, gcursor, dis, row_start, row_end, ssrc);

    const int GEMM_BLOCKS = (NN + 63) / 64;   // 1563
    gemm_mfma_kernel<128, false><<<GEMM_BLOCKS, 256, 0, stream>>>(x, W1, dis, g1, NN);

    const int AGG_BLOCKS = (NN + 3) / 4;      // 25000 (4 waves/block)
    agg128_kernel<<<AGG_BLOCKS, 256, 0, stream>>>(g1, row_start, row_end, ssrc, dis, b1, h);

    hipMemsetAsync((char*)g2 + (size_t)NN * 128, 0, 128, stream);   // g2 zero row (g1 now dead)

    gemm_mfma_kernel<64, true><<<GEMM_BLOCKS, 256, 0, stream>>>(h, W2, dis, g2, NN);

    agg64_kernel<<<AGG_BLOCKS, 256, 0, stream>>>(g2, row_start, row_end, ssrc, dis, b2, out);
}